// Round 2
// baseline (164.413 us; speedup 1.0000x reference)
//
#include <hip/hip_runtime.h>
#include <hip/hip_cooperative_groups.h>

// SeparationLoss: landmarks [B=1024, N=256, D=2] fp32 -> scalar fp32
//   sum_b sum_{i<j} d2 * exp(-d2/25),  d2 = ||x_i - x_j||^2
//
// v3: single cooperative kernel (was fill+main+reduce = 3 graph nodes ->
// now fill+fused = 2). Round-1 accounting: harness ws-poison fill = 40.3us
// (structural), sep_main ~5us, sep_reduce ~2us => ~13us was inter-node
// gap/launch overhead. Fusing the reduce via grid.sync() removes one
// kernel node + one gap.
//
// Math (verified v2, absmax=0): circular pairing, thread i pairs with
// (i+j) mod 256 for j=1..127 full weight + j=128 half weight (pair hit
// twice). Points duplicated in LDS so (i+j) needs no modulo ->
// imm-offset ds_read_b64, 2-way bank alias = free (m136).
// Coordinates pre-scaled by g=sqrt(log2(e)/25) at LDS fill:
// u = |Pi-Pj|^2 -> term = u*exp2(-u)/k; neg folds into VOP3 modifier on
// v_exp_f32 => 5 VALU + 1 exp per pair. Final scale 25*ln2 once.
// 4 accumulators break the strict-FP serial add chain.
//
// Cooperative residency: 1024 blocks x 256 thr, __launch_bounds__(256,4)
// = 4 blocks/CU needed; cap is 8 (VGPR<=128, LDS 4KB) -> 2x margin.

namespace cg = cooperative_groups;

#define N_PTS 256
#define SCALE_G 0.2402244818f   // sqrt(log2(e)/25)
#define INV_K   17.328679514f   // 25*ln(2)

__device__ __forceinline__ float fast_exp2(float x) {
#if __has_builtin(__builtin_amdgcn_exp2f)
    return __builtin_amdgcn_exp2f(x);
#else
    return exp2f(x);
#endif
}

#define PAIR(Q, ACC) do { \
    float dx_ = xi - (Q).x, dy_ = yi - (Q).y; \
    float u_ = dx_ * dx_ + dy_ * dy_; \
    ACC += u_ * fast_exp2(-u_); \
} while (0)

__global__ __launch_bounds__(256, 4) void sep_all(
    const float* __restrict__ lm, float* __restrict__ partial,
    float* __restrict__ out) {
    __shared__ float2 pts[2 * N_PTS];
    __shared__ float wsum[4];
    const int b = blockIdx.x;
    const int t = threadIdx.x;

    const float2* src = (const float2*)(lm + (size_t)b * N_PTS * 2);
    float2 p = src[t];        // coalesced 8B/lane
    p.x *= SCALE_G;
    p.y *= SCALE_G;
    pts[t] = p;
    pts[t + N_PTS] = p;       // duplicate: kills the modulo
    __syncthreads();

    const float xi = p.x, yi = p.y;
    const float2* row = &pts[t];

    float s0 = 0.f, s1 = 0.f, s2 = 0.f, s3 = 0.f;
    // offsets 1..124: 31 groups of 4
#pragma unroll 4
    for (int j = 1; j <= 121; j += 4) {
        float2 q0 = row[j];
        float2 q1 = row[j + 1];
        float2 q2 = row[j + 2];
        float2 q3 = row[j + 3];
        PAIR(q0, s0); PAIR(q1, s1); PAIR(q2, s2); PAIR(q3, s3);
    }
    // singles 125..127 full weight, 128 half weight (each pair hit twice)
    {
        float2 q0 = row[125];
        float2 q1 = row[126];
        float2 q2 = row[127];
        float2 q3 = row[128];
        PAIR(q0, s0); PAIR(q1, s1); PAIR(q2, s2);
        float dx_ = xi - q3.x, dy_ = yi - q3.y;
        float u_ = dx_ * dx_ + dy_ * dy_;
        s3 += 0.5f * u_ * fast_exp2(-u_);
    }

    float s = (s0 + s1) + (s2 + s3);

    // wave butterfly reduce (64 lanes)
    for (int off = 32; off > 0; off >>= 1) s += __shfl_down(s, off, 64);

    if ((t & 63) == 0) wsum[t >> 6] = s;
    __syncthreads();
    if (t == 0) partial[b] = (wsum[0] + wsum[1]) + (wsum[2] + wsum[3]);

    // ---- grid-wide rendezvous, then block 0 folds the 1024 partials ----
    __threadfence();          // release partials to device scope
    cg::this_grid().sync();

    if (b == 0) {
        const float4* p4 = (const float4*)partial;  // 1024 floats = 256 x float4
        float4 v = p4[t];
        float r = (v.x + v.y) + (v.z + v.w);
        for (int off = 32; off > 0; off >>= 1) r += __shfl_down(r, off, 64);
        if ((t & 63) == 0) wsum[t >> 6] = r;
        __syncthreads();
        if (t == 0)
            out[0] = ((wsum[0] + wsum[1]) + (wsum[2] + wsum[3])) * INV_K;
    }
}

extern "C" void kernel_launch(void* const* d_in, const int* in_sizes, int n_in,
                              void* d_out, int out_size, void* d_ws, size_t ws_size,
                              hipStream_t stream) {
    const float* landmarks = (const float*)d_in[0];
    float* out = (float*)d_out;
    float* partial = (float*)d_ws;            // 1024 floats = 4 KB

    const int B = in_sizes[0] / (N_PTS * 2);  // 1024

    void* args[] = {(void*)&landmarks, (void*)&partial, (void*)&out};
    hipLaunchCooperativeKernel((void*)sep_all, dim3(B), dim3(N_PTS), args, 0,
                               stream);
}

// Round 3
// 69.879 us; speedup vs baseline: 2.3528x; 2.3528x over previous
//
#include <hip/hip_runtime.h>

// SeparationLoss: landmarks [B=1024, N=256, D=2] fp32 -> scalar fp32
//   sum_b sum_{i<j} d2 * exp(-d2/25),  d2 = ||x_i - x_j||^2
//
// v4: memset(out,4B) + single kernel with one fp32 atomicAdd per block.
//   - v3 post-mortem: cg::this_grid().sync() on 1024 blocks costs ~90us
//     (sep_all dispatch = 100us, VALUBusy 5%) -> grid barriers are NOT a
//     cheap way to fuse; reverted.
//   - v2 structure was fill(40.3us, harness, structural) + main + reduce
//     + 2 node gaps. Replacing the reduce kernel with a 4-byte memset
//     node + 1024 atomicAdds removes one kernel + one gap; ws partials
//     are gone entirely (harness still poisons ws, we just don't use it).
//   - 1024 atomic adds to one address serialize at ~ns each: negligible.
//     fp32 atomic ordering noise << 1% tolerance (output ~1.07e8).
//
// Math (verified absmax=0 in v2/v3): circular pairing, thread i pairs
// with (i+j) mod 256, j=1..127 full weight + j=128 half weight (each
// such pair generated twice). Points duplicated in LDS so (i+j) needs no
// modulo -> imm-offset ds_read_b64; stride-8B across lanes = 2-way bank
// alias = free (m136). Coordinates pre-scaled by g=sqrt(log2(e)/25):
// u = |Pi-Pj|^2 -> term = u*exp2(-u); neg folds into the VOP3 input
// modifier on v_exp_f32 => 5 full-rate VALU + 1 trans per pair.
// Final scale 25*ln2 applied per block before the atomic.
// 4 accumulators break the strict-FP serial add chain.

#define N_PTS 256
#define SCALE_G 0.2402244818f   // sqrt(log2(e)/25)
#define INV_K   17.328679514f   // 25*ln(2)

__device__ __forceinline__ float fast_exp2(float x) {
#if __has_builtin(__builtin_amdgcn_exp2f)
    return __builtin_amdgcn_exp2f(x);
#else
    return exp2f(x);
#endif
}

#define PAIR(Q, ACC) do { \
    float dx_ = xi - (Q).x, dy_ = yi - (Q).y; \
    float u_ = dx_ * dx_ + dy_ * dy_; \
    ACC += u_ * fast_exp2(-u_); \
} while (0)

__global__ __launch_bounds__(256) void sep_main(
    const float* __restrict__ lm, float* __restrict__ out) {
    __shared__ float2 pts[2 * N_PTS];
    __shared__ float wsum[4];
    const int b = blockIdx.x;
    const int t = threadIdx.x;

    const float2* src = (const float2*)(lm + (size_t)b * N_PTS * 2);
    float2 p = src[t];        // coalesced 8B/lane
    p.x *= SCALE_G;
    p.y *= SCALE_G;
    pts[t] = p;
    pts[t + N_PTS] = p;       // duplicate: kills the modulo
    __syncthreads();

    const float xi = p.x, yi = p.y;
    const float2* row = &pts[t];

    float s0 = 0.f, s1 = 0.f, s2 = 0.f, s3 = 0.f;
    // offsets 1..124: 31 groups of 4
#pragma unroll 4
    for (int j = 1; j <= 121; j += 4) {
        float2 q0 = row[j];
        float2 q1 = row[j + 1];
        float2 q2 = row[j + 2];
        float2 q3 = row[j + 3];
        PAIR(q0, s0); PAIR(q1, s1); PAIR(q2, s2); PAIR(q3, s3);
    }
    // singles 125..127 full weight, 128 half weight (each pair hit twice)
    {
        float2 q0 = row[125];
        float2 q1 = row[126];
        float2 q2 = row[127];
        float2 q3 = row[128];
        PAIR(q0, s0); PAIR(q1, s1); PAIR(q2, s2);
        float dx_ = xi - q3.x, dy_ = yi - q3.y;
        float u_ = dx_ * dx_ + dy_ * dy_;
        s3 += 0.5f * u_ * fast_exp2(-u_);
    }

    float s = (s0 + s1) + (s2 + s3);

    // wave butterfly reduce (64 lanes)
    for (int off = 32; off > 0; off >>= 1) s += __shfl_down(s, off, 64);

    if ((t & 63) == 0) wsum[t >> 6] = s;
    __syncthreads();
    if (t == 0) {
        float blk = (wsum[0] + wsum[1]) + (wsum[2] + wsum[3]);
        atomicAdd(out, blk * INV_K);   // device-scope fp32 atomic
    }
}

extern "C" void kernel_launch(void* const* d_in, const int* in_sizes, int n_in,
                              void* d_out, int out_size, void* d_ws, size_t ws_size,
                              hipStream_t stream) {
    const float* landmarks = (const float*)d_in[0];
    float* out = (float*)d_out;

    const int B = in_sizes[0] / (N_PTS * 2);  // 1024

    hipMemsetAsync(out, 0, out_size, stream); // 4-byte node, graph-capturable
    sep_main<<<B, N_PTS, 0, stream>>>(landmarks, out);
}

// Round 4
// 62.281 us; speedup vs baseline: 2.6398x; 1.1220x over previous
//
#include <hip/hip_runtime.h>

// SeparationLoss: landmarks [B=1024, N=256, D=2] fp32 -> scalar fp32
//   sum_b sum_{i<j} d2 * exp(-d2/25),  d2 = ||x_i - x_j||^2
//
// v5: revert to the proven v2 3-node structure (fill + main + reduce),
// split main one step further: 4096 blocks, 32 circular offsets/thread.
//   Ledger: v3 grid.sync = ~90us (NO). v4 1024 same-address atomics =
//   +8.5us serialization (NO). v2 plain-store + tiny reduce = best
//   (61.36us). v1->v2 (128->64 iters/thread) = -1us => main is partly
//   latency-bound; halve the serial chain again (64->32).
//
// Math (verified absmax=0): circular pairing, thread i pairs with
// (i+j) mod 256; j=1..127 full weight + j=128 half weight (each such
// pair generated twice). Block quarter q owns offsets q*32+1..q*32+32
// (q=3: 97..127 full + 128 half). Points duplicated in LDS so (i+j)
// needs no modulo -> imm-offset ds_read_b64; stride-8B across lanes =
// 2-way bank alias = free (m136). Coordinates pre-scaled by
// g=sqrt(log2(e)/25): u = |Pi-Pj|^2 -> term = u*exp2(-u); negation
// folds into the VOP3 input modifier on v_exp_f32 => 5 full-rate VALU
// + 1 trans per pair. Final scale 25*ln2 once in reduce.
// 4 accumulators break the strict-FP serial add chain.

#define N_PTS 256
#define SCALE_G 0.2402244818f   // sqrt(log2(e)/25)
#define INV_K   17.328679514f   // 25*ln(2)

__device__ __forceinline__ float fast_exp2(float x) {
#if __has_builtin(__builtin_amdgcn_exp2f)
    return __builtin_amdgcn_exp2f(x);
#else
    return exp2f(x);
#endif
}

#define PAIR(Q, ACC) do { \
    float dx_ = xi - (Q).x, dy_ = yi - (Q).y; \
    float u_ = dx_ * dx_ + dy_ * dy_; \
    ACC += u_ * fast_exp2(-u_); \
} while (0)

__global__ __launch_bounds__(256, 8) void sep_main(
    const float* __restrict__ lm, float* __restrict__ partial) {
    __shared__ float2 pts[2 * N_PTS];
    __shared__ float wsum[4];
    const int blk = blockIdx.x;
    const int b = blk >> 2;   // batch index
    const int q = blk & 3;    // offset quarter: q*32+1 .. q*32+32
    const int t = threadIdx.x;

    const float2* src = (const float2*)(lm + (size_t)b * N_PTS * 2);
    float2 p = src[t];        // coalesced 8B/lane
    p.x *= SCALE_G;
    p.y *= SCALE_G;
    pts[t] = p;
    pts[t + N_PTS] = p;       // duplicate: kills the modulo
    __syncthreads();

    const float xi = p.x, yi = p.y;
    const float2* row = &pts[t];
    const int j0 = q * 32 + 1;

    float s0 = 0.f, s1 = 0.f, s2 = 0.f, s3 = 0.f;
    if (q < 3) {
        // 32 full-weight offsets: 8 groups of 4
#pragma unroll 8
        for (int j = j0; j < j0 + 32; j += 4) {
            float2 q0 = row[j];
            float2 q1 = row[j + 1];
            float2 q2 = row[j + 2];
            float2 q3 = row[j + 3];
            PAIR(q0, s0); PAIR(q1, s1); PAIR(q2, s2); PAIR(q3, s3);
        }
    } else {
        // offsets 97..124: 7 groups of 4
#pragma unroll 7
        for (int j = 97; j <= 121; j += 4) {
            float2 q0 = row[j];
            float2 q1 = row[j + 1];
            float2 q2 = row[j + 2];
            float2 q3 = row[j + 3];
            PAIR(q0, s0); PAIR(q1, s1); PAIR(q2, s2); PAIR(q3, s3);
        }
        // singles 125..127 full weight, 128 half weight (pair hit twice)
        float2 q0 = row[125];
        float2 q1 = row[126];
        float2 q2 = row[127];
        float2 q3 = row[128];
        PAIR(q0, s0); PAIR(q1, s1); PAIR(q2, s2);
        float dx_ = xi - q3.x, dy_ = yi - q3.y;
        float u_ = dx_ * dx_ + dy_ * dy_;
        s3 += 0.5f * u_ * fast_exp2(-u_);
    }

    float s = (s0 + s1) + (s2 + s3);

    // wave butterfly reduce (64 lanes)
    for (int off = 32; off > 0; off >>= 1) s += __shfl_down(s, off, 64);

    if ((t & 63) == 0) wsum[t >> 6] = s;
    __syncthreads();
    if (t == 0) partial[blk] = (wsum[0] + wsum[1]) + (wsum[2] + wsum[3]);
}

__global__ __launch_bounds__(256) void sep_reduce(
    const float* __restrict__ partial, float* __restrict__ out, int n4) {
    const int t = threadIdx.x;
    const float4* p4 = (const float4*)partial;
    float s = 0.f;
    for (int i = t; i < n4; i += 256) {   // 4096 partials = 4 float4/thread
        float4 v = p4[i];
        s += (v.x + v.y) + (v.z + v.w);
    }
    for (int off = 32; off > 0; off >>= 1) s += __shfl_down(s, off, 64);
    __shared__ float wsum[4];
    if ((t & 63) == 0) wsum[t >> 6] = s;
    __syncthreads();
    if (t == 0)
        out[0] = ((wsum[0] + wsum[1]) + (wsum[2] + wsum[3])) * INV_K;
}

extern "C" void kernel_launch(void* const* d_in, const int* in_sizes, int n_in,
                              void* d_out, int out_size, void* d_ws, size_t ws_size,
                              hipStream_t stream) {
    const float* landmarks = (const float*)d_in[0];
    float* out = (float*)d_out;
    float* partial = (float*)d_ws;            // 4096 floats = 16 KB

    const int B = in_sizes[0] / (N_PTS * 2);  // 1024

    sep_main<<<4 * B, N_PTS, 0, stream>>>(landmarks, partial);
    sep_reduce<<<1, N_PTS, 0, stream>>>(partial, out, B);
}

// Round 5
// 61.502 us; speedup vs baseline: 2.6733x; 1.0127x over previous
//
#include <hip/hip_runtime.h>

// SeparationLoss: landmarks [B=1024, N=256, D=2] fp32 -> scalar fp32
//   sum_b sum_{i<j} d2 * exp(-d2/25),  d2 = ||x_i - x_j||^2
//
// v6 = exact revert to v2, the measured-best structure (61.36us).
// Ledger (all measured):
//   v2  fill+main(2048)+reduce : 61.36  <- best, this kernel
//   v1  fill+main(1024)+reduce : 62.39  (128 iters/thread: latency)
//   v5  fill+main(4096)+reduce : 62.28  (split past the knee: null)
//   v4  fill+memset+atomicmain : 69.88  (1024 same-addr atomics +8.5us)
//   v3  fill+coop-fused        : 164.4  (grid.sync ~90us on 1024 blocks)
// Structural floor: 40.3us harness ws-poison fill (83% HBM peak, present
// even when ws is unused - proven in v4) + ~13us 3-node graph overhead
// (both node-reduction alternatives measured worse) + ~6.5us of kernels
// already near the VALU/trans roofline (5 VALU + 1 v_exp_f32 per pair).
//
// Math (verified absmax=0): circular pairing, thread i pairs with
// (i+j) mod 256; j=1..127 full weight + j=128 half weight (each such
// pair generated twice -> 0.5x). Block half h owns offsets 1..64 |
// 65..128. Points duplicated in LDS so (i+j) needs no modulo ->
// imm-offset ds_read_b64; stride-8B across lanes = 2-way bank alias =
// free (m136). Coordinates pre-scaled by g=sqrt(log2(e)/25):
// u = |Pi-Pj|^2 -> term = u*exp2(-u); negation folds into the VOP3
// input modifier on v_exp_f32. Final scale 25*ln2 once in reduce.
// 4 accumulators break the strict-FP serial add chain.

#define N_PTS 256
#define SCALE_G 0.2402244818f   // sqrt(log2(e)/25)
#define INV_K   17.328679514f   // 25*ln(2)

__device__ __forceinline__ float fast_exp2(float x) {
#if __has_builtin(__builtin_amdgcn_exp2f)
    return __builtin_amdgcn_exp2f(x);
#else
    return exp2f(x);
#endif
}

#define PAIR(Q, ACC) do { \
    float dx_ = xi - (Q).x, dy_ = yi - (Q).y; \
    float u_ = dx_ * dx_ + dy_ * dy_; \
    ACC += u_ * fast_exp2(-u_); \
} while (0)

__global__ __launch_bounds__(256, 8) void sep_main(
    const float* __restrict__ lm, float* __restrict__ partial) {
    __shared__ float2 pts[2 * N_PTS];
    __shared__ float wsum[4];
    const int blk = blockIdx.x;
    const int b = blk >> 1;   // batch index
    const int hi = blk & 1;   // 0: offsets 1..64, 1: offsets 65..128
    const int t = threadIdx.x;

    const float2* src = (const float2*)(lm + (size_t)b * N_PTS * 2);
    float2 p = src[t];        // coalesced 8B/lane
    p.x *= SCALE_G;
    p.y *= SCALE_G;
    pts[t] = p;
    pts[t + N_PTS] = p;       // duplicate: kills the modulo
    __syncthreads();

    const float xi = p.x, yi = p.y;
    const float2* row = &pts[t];

    float s0 = 0.f, s1 = 0.f, s2 = 0.f, s3 = 0.f;
    if (hi == 0) {
        // offsets 1..64: 16 groups of 4
#pragma unroll 4
        for (int j = 1; j <= 61; j += 4) {
            float2 q0 = row[j];
            float2 q1 = row[j + 1];
            float2 q2 = row[j + 2];
            float2 q3 = row[j + 3];
            PAIR(q0, s0); PAIR(q1, s1); PAIR(q2, s2); PAIR(q3, s3);
        }
    } else {
        // offsets 65..124: 15 groups of 4
#pragma unroll 4
        for (int j = 65; j <= 121; j += 4) {
            float2 q0 = row[j];
            float2 q1 = row[j + 1];
            float2 q2 = row[j + 2];
            float2 q3 = row[j + 3];
            PAIR(q0, s0); PAIR(q1, s1); PAIR(q2, s2); PAIR(q3, s3);
        }
        // singles 125..127 full weight, 128 half weight (pair hit twice)
        float2 q0 = row[125];
        float2 q1 = row[126];
        float2 q2 = row[127];
        float2 q3 = row[128];
        PAIR(q0, s0); PAIR(q1, s1); PAIR(q2, s2);
        {
            float dx_ = xi - q3.x, dy_ = yi - q3.y;
            float u_ = dx_ * dx_ + dy_ * dy_;
            s3 += 0.5f * u_ * fast_exp2(-u_);
        }
    }

    float s = (s0 + s1) + (s2 + s3);

    // wave butterfly reduce (64 lanes)
    for (int off = 32; off > 0; off >>= 1) s += __shfl_down(s, off, 64);

    if ((t & 63) == 0) wsum[t >> 6] = s;
    __syncthreads();
    if (t == 0) partial[blk] = (wsum[0] + wsum[1]) + (wsum[2] + wsum[3]);
}

__global__ __launch_bounds__(256) void sep_reduce(
    const float* __restrict__ partial, float* __restrict__ out, int n4) {
    const int t = threadIdx.x;
    const float4* p4 = (const float4*)partial;
    float s = 0.f;
    for (int i = t; i < n4; i += 256) {
        float4 v = p4[i];
        s += (v.x + v.y) + (v.z + v.w);
    }
    for (int off = 32; off > 0; off >>= 1) s += __shfl_down(s, off, 64);
    __shared__ float wsum[4];
    if ((t & 63) == 0) wsum[t >> 6] = s;
    __syncthreads();
    if (t == 0)
        out[0] = ((wsum[0] + wsum[1]) + (wsum[2] + wsum[3])) * INV_K;
}

extern "C" void kernel_launch(void* const* d_in, const int* in_sizes, int n_in,
                              void* d_out, int out_size, void* d_ws, size_t ws_size,
                              hipStream_t stream) {
    const float* landmarks = (const float*)d_in[0];
    float* out = (float*)d_out;
    float* partial = (float*)d_ws;            // 2048 floats = 8 KB

    const int B = in_sizes[0] / (N_PTS * 2);  // 1024

    sep_main<<<2 * B, N_PTS, 0, stream>>>(landmarks, partial);
    sep_reduce<<<1, N_PTS, 0, stream>>>(partial, out, (2 * B) / 4);
}